// Round 1
// 545.130 us; speedup vs baseline: 1.0358x; 1.0358x over previous
//
#include <hip/hip_runtime.h>
#include <hip/hip_bf16.h>

#define BATCH 32768
#define IN_DIM 64
#define NUM_CLASSES 4096

typedef short bf16x8 __attribute__((ext_vector_type(8)));   // 8 bf16 = 4 VGPRs
typedef float f32x4 __attribute__((ext_vector_type(4)));    // MFMA 16x16 accumulator

// Convert fp32 rows (length 64) to bf16 and emit per-row sum of squares (fp32).
// One float4 (4 elements) per thread; a row = 16 consecutive threads.
__global__ void convert_rows(const float* __restrict__ src,
                             unsigned short* __restrict__ dst,
                             float* __restrict__ sq) {
    int t = blockIdx.x * blockDim.x + threadIdx.x;
    float4 v = ((const float4*)src)[t];

    __hip_bfloat16 h0 = __float2bfloat16(v.x);
    __hip_bfloat16 h1 = __float2bfloat16(v.y);
    __hip_bfloat16 h2 = __float2bfloat16(v.z);
    __hip_bfloat16 h3 = __float2bfloat16(v.w);
    ushort4 o;
    o.x = __builtin_bit_cast(unsigned short, h0);
    o.y = __builtin_bit_cast(unsigned short, h1);
    o.z = __builtin_bit_cast(unsigned short, h2);
    o.w = __builtin_bit_cast(unsigned short, h3);
    ((ushort4*)dst)[t] = o;

    // fp32 sum of squares (exact path for the -x.x term)
    float s = v.x * v.x + v.y * v.y + v.z * v.z + v.w * v.w;
    s += __shfl_xor(s, 1, 16);
    s += __shfl_xor(s, 2, 16);
    s += __shfl_xor(s, 4, 16);
    s += __shfl_xor(s, 8, 16);
    if ((threadIdx.x & 15) == 0) sq[t >> 4] = s;
}

// logits[m][n] = 2*dot(x[m], w[n]) - xsq[m] - wsq[n]
// Block tile 128x128, 4 waves in 2x2, each wave 64x64 via 4x4 frags of 16x16x32.
//
// MFMA operands are SWAPPED relative to the classic form: mfma(b, a, acc) gives
//   acc[i][j][e] = cross[x-row m0+i*16+r][w-col n0+j*16+quad*4+e]
// so every thread owns 4 CONTIGUOUS floats of one output row (dwordx4-ready).
//
// Epilogue: per-wave private 8 KiB LDS transpose (XOR-swizzled 16B slots) so the
// final global stores are fully-contiguous 256-B runs per 16 lanes (whole 128-B
// lines per transaction), replicating the streaming pattern that hits 6.3 TB/s.
__global__ __launch_bounds__(256) void rbf_gemm(
    const unsigned short* __restrict__ xb,   // [BATCH][64] bf16
    const unsigned short* __restrict__ wb,   // [NUM_CLASSES][64] bf16
    const float* __restrict__ xsq,           // [BATCH]
    const float* __restrict__ wsq,           // [NUM_CLASSES]
    float* __restrict__ out)                 // [BATCH][NUM_CLASSES]
{
    __shared__ float lds[4 * 2048];          // 4 waves x 8 KiB (32 KiB total)

    const int bid    = blockIdx.x;
    const int tile_n = bid & 31;     // 4096/128 = 32 n-tiles (fast-varying: w L2 reuse)
    const int tile_m = bid >> 5;     // 32768/128 = 256 m-tiles
    const int lane   = threadIdx.x & 63;
    const int wave   = threadIdx.x >> 6;
    const int wm     = wave >> 1;
    const int wn     = wave & 1;
    const int m0     = tile_m * 128 + wm * 64;
    const int n0     = tile_n * 128 + wn * 64;
    const int r      = lane & 15;
    const int quad   = lane >> 4;

    const unsigned short* arow = xb + (size_t)(m0 + r) * IN_DIM + quad * 8;
    const unsigned short* brow = wb + (size_t)(n0 + r) * IN_DIM + quad * 8;

    bf16x8 a[4][2], b[4][2];
#pragma unroll
    for (int i = 0; i < 4; ++i) {
#pragma unroll
        for (int s = 0; s < 2; ++s) {
            a[i][s] = *(const bf16x8*)(arow + i * 16 * IN_DIM + s * 32);
            b[i][s] = *(const bf16x8*)(brow + i * 16 * IN_DIM + s * 32);
        }
    }

    f32x4 acc[4][4];
#pragma unroll
    for (int i = 0; i < 4; ++i)
#pragma unroll
        for (int j = 0; j < 4; ++j)
            acc[i][j] = (f32x4)0.0f;

    // SWAPPED operand order: D[row][col] with row = w-offset (quad*4+reg),
    // col = x-offset (r). Fragment layouts are symmetric (both loaded row-major
    // with r = lane&15, k-chunk = quad*8), so this is a pure index remap.
#pragma unroll
    for (int s = 0; s < 2; ++s)
#pragma unroll
        for (int i = 0; i < 4; ++i)
#pragma unroll
            for (int j = 0; j < 4; ++j)
                acc[i][j] = __builtin_amdgcn_mfma_f32_16x16x32_bf16(
                    b[j][s], a[i][s], acc[i][j], 0, 0, 0);

    // Per-thread epilogue operands.
    // Thread's output rows: m0 + i*16 + r  (i = 0..3)
    // Thread's output cols: n0 + j*16 + quad*4 + e  (j = 0..3, e = 0..3)
    float xs[4];
#pragma unroll
    for (int i = 0; i < 4; ++i) xs[i] = xsq[m0 + i * 16 + r];

    f32x4 wv[4];
#pragma unroll
    for (int j = 0; j < 4; ++j)
        wv[j] = *(const f32x4*)(wsq + n0 + j * 16 + quad * 4);

    char* my = (char*)(lds + wave * 2048);   // wave-private 8 KiB: 32 rows x 256 B

    // Two halves of 32 rows each (i = 2h, 2h+1) through the same LDS region.
#pragma unroll
    for (int h = 0; h < 2; ++h) {
        // ---- write phase: deposit finished logits into swizzled LDS ----
#pragma unroll
        for (int ii = 0; ii < 2; ++ii) {
            const int i  = 2 * h + ii;
            const int rl = ii * 16 + r;                       // local row 0..31
            const int swz = (rl & 7) << 4;                    // 16-B slot XOR
#pragma unroll
            for (int j = 0; j < 4; ++j) {
                f32x4 v;
                v[0] = 2.0f * acc[i][j][0] - xs[i] - wv[j][0];
                v[1] = 2.0f * acc[i][j][1] - xs[i] - wv[j][1];
                v[2] = 2.0f * acc[i][j][2] - xs[i] - wv[j][2];
                v[3] = 2.0f * acc[i][j][3] - xs[i] - wv[j][3];
                const int byte = rl * 256 + (((j * 4 + quad) * 16) ^ swz);
                *(f32x4*)(my + byte) = v;
            }
        }
        __syncthreads();

        // ---- read phase: row-major readback, fully-coalesced wide stores ----
        // Per instruction: 4 rows x 256-B contiguous runs (16 B/lane).
#pragma unroll
        for (int p = 0; p < 8; ++p) {
            const int rl  = p * 4 + quad;                     // local row 0..31
            const int swz = (rl & 7) << 4;
            f32x4 v = *(const f32x4*)(my + rl * 256 + ((r * 16) ^ swz));
            *(f32x4*)(out + (size_t)(m0 + h * 32 + rl) * NUM_CLASSES
                          + n0 + r * 4) = v;
        }
        if (h == 0) __syncthreads();                          // WAR before reuse
    }
}

extern "C" void kernel_launch(void* const* d_in, const int* in_sizes, int n_in,
                              void* d_out, int out_size, void* d_ws, size_t ws_size,
                              hipStream_t stream) {
    const float* x = (const float*)d_in[0];   // [32768, 64] fp32
    const float* w = (const float*)d_in[1];   // [4096, 64] fp32, values +/-1
    float* out = (float*)d_out;               // [32768, 4096] fp32

    // Workspace layout (~4.66 MiB total):
    char* ws = (char*)d_ws;
    unsigned short* xb = (unsigned short*)ws;                                   // 4 MiB
    unsigned short* wb = (unsigned short*)(ws + (size_t)BATCH * IN_DIM * 2);    // 512 KiB
    float* xsq = (float*)(ws + (size_t)BATCH * IN_DIM * 2
                             + (size_t)NUM_CLASSES * IN_DIM * 2);               // 128 KiB
    float* wsq = xsq + BATCH;                                                   // 16 KiB

    convert_rows<<<(BATCH * IN_DIM / 4) / 256, 256, 0, stream>>>(x, xb, xsq);
    convert_rows<<<(NUM_CLASSES * IN_DIM / 4) / 256, 256, 0, stream>>>(w, wb, wsq);

    const int grid = (BATCH / 128) * (NUM_CLASSES / 128);  // 256 * 32 = 8192
    rbf_gemm<<<grid, 256, 0, stream>>>(xb, wb, xsq, wsq, out);
}